// Round 2
// baseline (102.747 us; speedup 1.0000x reference)
//
#include <hip/hip_runtime.h>
#include <hip/hip_bf16.h>

typedef __bf16 bf16x8 __attribute__((ext_vector_type(8)));
typedef __bf16 bf16x2 __attribute__((ext_vector_type(2)));
typedef float  floatx4 __attribute__((ext_vector_type(4)));

static constexpr int TWO_B = 8192;   // 2*B rows
static constexpr int CDIM  = 128;    // feature dim
// exp(x/T) = exp2(x * (1/T)/ln2), T = 0.5
#define SCALE 2.8853900817779268f
#define INV_T 2.0f

#if __has_builtin(__builtin_amdgcn_exp2f)
#define EXP2F(x) __builtin_amdgcn_exp2f(x)
#else
#define EXP2F(x) exp2f(x)
#endif

// ---------------------------------------------------------------------------
// Kernel 1: L2-normalize each of the 8192 rows; write fp32 + bf16 copies.
// One wave per row (lane holds 2 elements).
// ---------------------------------------------------------------------------
__global__ __launch_bounds__(256) void nk(const float* __restrict__ zi,
                                          const float* __restrict__ zj,
                                          float* __restrict__ nf,
                                          __bf16* __restrict__ nb) {
    const int w = threadIdx.x >> 6, lane = threadIdx.x & 63;
    const int row = blockIdx.x * 4 + w;
    const float* src = (row < 4096) ? (zi + row * CDIM) : (zj + (row - 4096) * CDIM);
    float2 x = reinterpret_cast<const float2*>(src)[lane];
    float ss = x.x * x.x + x.y * x.y;
#pragma unroll
    for (int m = 1; m < 64; m <<= 1) ss += __shfl_xor(ss, m, 64);
    const float rn = rsqrtf(ss);
    float2 y; y.x = x.x * rn; y.y = x.y * rn;
    reinterpret_cast<float2*>(nf + row * CDIM)[lane] = y;
    bf16x2 b; b[0] = (__bf16)y.x; b[1] = (__bf16)y.y;
    reinterpret_cast<bf16x2*>(nb + row * CDIM)[lane] = b;
}

// ---------------------------------------------------------------------------
// Kernel 2: per-row sum of exp(sim[r,j]/T) over a 512-column slice.
// Block = 256 thr (4 waves). Each block: 128 rows (wave w -> rows w*32..+32,
// two 16-row m-subtiles). Columns streamed in 64-wide tiles staged to LDS via
// global_load_lds (16B), XOR-swizzled so ds_read_b128 B-frag reads are
// conflict-free. Grid: (64 row tiles, 16 column splits). Partials written
// per (split,row) — no atomics, no memset needed.
// ---------------------------------------------------------------------------
__global__ __launch_bounds__(256) void sk(const __bf16* __restrict__ nb,
                                          float* __restrict__ partial) {
    const int rt  = blockIdx.x;   // 0..63
    const int csp = blockIdx.y;   // 0..15
    const int tid = threadIdx.x;
    const int w   = tid >> 6;
    const int lane = tid & 63;
    const int l15 = lane & 15;
    const int lg  = lane >> 4;

    __shared__ __bf16 ldsB[64 * CDIM];   // 16 KB

    // A fragments: 32 rows x 128 k per wave, kept in registers.
    // A-layout: m = lane&15, k = (lane>>4)*8 + j  (per 32-wide k-step)
    const int rowbase = rt * 128 + w * 32;
    bf16x8 afrag[2][4];
#pragma unroll
    for (int mi = 0; mi < 2; ++mi)
#pragma unroll
        for (int kq = 0; kq < 4; ++kq)
            afrag[mi][kq] = *reinterpret_cast<const bf16x8*>(
                nb + (rowbase + mi * 16 + l15) * CDIM + kq * 32 + lg * 8);

    float rowsum[2][4];
#pragma unroll
    for (int mi = 0; mi < 2; ++mi)
#pragma unroll
        for (int r = 0; r < 4; ++r) rowsum[mi][r] = 0.0f;

    const int colbase0 = csp * 512;
    for (int ct = 0; ct < 8; ++ct) {
        const int colbase = colbase0 + ct * 64;
        __syncthreads();   // previous tile's compute done before overwrite
        // Stage 64 rows x 256 B. LDS slot s (16B) <- global chunk
        // (R = s>>4, c = (s&15) ^ (R&15))  — XOR swizzle kills bank conflicts.
#pragma unroll
        for (int i = 0; i < 4; ++i) {
            const int s = i * 256 + tid;          // per-wave: uniform base + lane*16
            const int R = s >> 4, cs = s & 15;
            const int gc = cs ^ (R & 15);
            const __bf16* g = nb + (colbase + R) * CDIM + gc * 8;
            __builtin_amdgcn_global_load_lds(
                (__attribute__((address_space(1))) void*)g,
                (__attribute__((address_space(3))) void*)(ldsB + s * 8),
                16, 0, 0);
        }
        __syncthreads();   // compiler emits vmcnt(0) drain before barrier

#pragma unroll
        for (int ni = 0; ni < 4; ++ni) {
            floatx4 acc0 = {0.f, 0.f, 0.f, 0.f};
            floatx4 acc1 = {0.f, 0.f, 0.f, 0.f};
#pragma unroll
            for (int kq = 0; kq < 4; ++kq) {
                // B-layout: n = lane&15 (local row R), k = (lane>>4)*8 + j
                const int R    = ni * 16 + l15;
                const int cg   = kq * 4 + lg;
                const int slot = R * 16 + (cg ^ (R & 15));
                bf16x8 bfrag = *reinterpret_cast<const bf16x8*>(ldsB + slot * 8);
                acc0 = __builtin_amdgcn_mfma_f32_16x16x32_bf16(afrag[0][kq], bfrag, acc0, 0, 0, 0);
                acc1 = __builtin_amdgcn_mfma_f32_16x16x32_bf16(afrag[1][kq], bfrag, acc1, 0, 0, 0);
            }
            // C/D layout: col = lane&15, row = (lane>>4)*4 + reg
#pragma unroll
            for (int r = 0; r < 4; ++r) {
                rowsum[0][r] += EXP2F(acc0[r] * SCALE);
                rowsum[1][r] += EXP2F(acc1[r] * SCALE);
            }
        }
    }

    // Sum across the 16 column-lanes within each lane-group.
#pragma unroll
    for (int mi = 0; mi < 2; ++mi)
#pragma unroll
        for (int r = 0; r < 4; ++r) {
            float v = rowsum[mi][r];
            v += __shfl_xor(v, 1, 64);
            v += __shfl_xor(v, 2, 64);
            v += __shfl_xor(v, 4, 64);
            v += __shfl_xor(v, 8, 64);
            rowsum[mi][r] = v;
        }
    if (l15 == 0) {
#pragma unroll
        for (int mi = 0; mi < 2; ++mi)
#pragma unroll
            for (int r = 0; r < 4; ++r)
                partial[csp * TWO_B + rowbase + mi * 16 + lg * 4 + r] = rowsum[mi][r];
    }
}

// ---------------------------------------------------------------------------
// Kernel 3: per-row finalize. One wave per row:
//   pos   = fp32 dot(n_r, n_partner)          (exact positive logit)
//   selfd = ||bf16(n_r)||^2                   (matches MFMA's diagonal value)
//   S     = sum_c partial[c][row] + exp(pos/T) - exp(selfd/T)
//   loss_r = log(S) - pos/T
// ---------------------------------------------------------------------------
__global__ __launch_bounds__(256) void fk(const float* __restrict__ nf,
                                          const __bf16* __restrict__ nb,
                                          const float* __restrict__ partial,
                                          float* __restrict__ rowloss) {
    const int w = threadIdx.x >> 6, lane = threadIdx.x & 63;
    const int row = blockIdx.x * 4 + w;
    const int partner = (row + 4096) & (TWO_B - 1);
    float2 a = reinterpret_cast<const float2*>(nf + row * CDIM)[lane];
    float2 b = reinterpret_cast<const float2*>(nf + partner * CDIM)[lane];
    float dot = a.x * b.x + a.y * b.y;
    bf16x2 sb = reinterpret_cast<const bf16x2*>(nb + row * CDIM)[lane];
    const float s0 = (float)sb[0], s1 = (float)sb[1];
    float sq = s0 * s0 + s1 * s1;
    float ps = (lane < 16) ? partial[lane * TWO_B + row] : 0.0f;
#pragma unroll
    for (int m = 1; m < 64; m <<= 1) {
        dot += __shfl_xor(dot, m, 64);
        sq  += __shfl_xor(sq,  m, 64);
        ps  += __shfl_xor(ps,  m, 64);
    }
    if (lane == 0) {
        const float S = ps + EXP2F(dot * SCALE) - EXP2F(sq * SCALE);
        rowloss[row] = __logf(S) - dot * INV_T;
    }
}

// ---------------------------------------------------------------------------
// Kernel 4: mean over 8192 row losses -> fp32 scalar (reference output dtype
// is float32 — writing bf16 here left the fp32 word ~0 and failed r1).
// ---------------------------------------------------------------------------
__global__ __launch_bounds__(256) void rk(const float* __restrict__ rowloss,
                                          float* __restrict__ out) {
    const int tid = threadIdx.x;
    float s = 0.f;
    for (int i = tid; i < TWO_B; i += 256) s += rowloss[i];
#pragma unroll
    for (int m = 1; m < 64; m <<= 1) s += __shfl_xor(s, m, 64);
    __shared__ float acc[4];
    if ((tid & 63) == 0) acc[tid >> 6] = s;
    __syncthreads();
    if (tid == 0)
        out[0] = (acc[0] + acc[1] + acc[2] + acc[3]) * (1.0f / TWO_B);
}

extern "C" void kernel_launch(void* const* d_in, const int* in_sizes, int n_in,
                              void* d_out, int out_size, void* d_ws, size_t ws_size,
                              hipStream_t stream) {
    const float* zi = (const float*)d_in[0];
    const float* zj = (const float*)d_in[1];
    char* ws = (char*)d_ws;
    float*  nf      = (float*)ws;                                  // 8192*128 f32 = 4 MB
    __bf16* nb      = (__bf16*)(ws + (size_t)TWO_B * CDIM * 4);    // 8192*128 bf16 = 2 MB
    float*  partial = (float*)(ws + (size_t)TWO_B * CDIM * 6);     // 16*8192 f32 = 512 KB
    float*  rowloss = (float*)(ws + (size_t)TWO_B * CDIM * 6 + (size_t)16 * TWO_B * 4);

    nk<<<TWO_B / 4, 256, 0, stream>>>(zi, zj, nf, nb);
    sk<<<dim3(64, 16), 256, 0, stream>>>(nb, partial);
    fk<<<TWO_B / 4, 256, 0, stream>>>(nf, nb, partial, rowloss);
    rk<<<1, 256, 0, stream>>>(rowloss, (float*)d_out);
}